// Round 6
// baseline (262.497 us; speedup 1.0000x reference)
//
#include <hip/hip_runtime.h>

// BSplineBasis: x[1048576], knots[64] (clamped cubic, 57 uniform interior
// intervals) -> out[1048576, 60] float32.
//
// Structure (R4/R5 post-mortems): 4096 independent blocks is the winning
// shape (cooperative single-kernel lost 2x on TLP starvation). Two-phase
// main kernel: per-row local de Boor -> LDS -> fully coalesced float4
// write-out, with the final min/max reduce fused into its head (every block
// redundantly reduces the 256 partials; 2 KB, L2-hot).
//
// R6 single change: NONTEMPORAL stores for the 240 MiB output stream
// (write-only, never re-read by the kernel; keep it out of L2). Isolated
// test — in R4 this was confounded with the cooperative-launch regression.
//
// Reference quirk we must reproduce: xn = (x - min)/(max - min + 1e-8) in
// fp32 loses the 1e-8 (range ~9.7, ulp ~1e-6), so the max element has
// xn == 1.0 exactly. The reference's half-open degree-0 indicator
// (x >= t[j]) & (x < t[j+1]) then yields an ALL-ZERO row for that element.
//
// Workspace (floats): [0..255] block mins, [256..511] block maxs (2 KB).

#define N_BASIS 60

typedef float f32x4_t __attribute__((ext_vector_type(4)));

__device__ __forceinline__ float fast_rcp(float a) {
    return __builtin_amdgcn_rcpf(a);  // ~1 ulp; threshold is 2e-2, fine
}

// ---------------- Kernel 1: per-block partial min/max ----------------
__global__ __launch_bounds__(256) void k_partial_minmax(
    const float* __restrict__ x, float* __restrict__ ws, int n4) {
    const int tid = threadIdx.x;
    int gid = blockIdx.x * 256 + tid;
    const int stride = gridDim.x * 256;
    const float4* __restrict__ x4 = (const float4*)x;

    float mn = 3.4028235e38f, mx = -3.4028235e38f;
    for (int i = gid; i < n4; i += stride) {
        float4 v = x4[i];
        mn = fminf(mn, fminf(fminf(v.x, v.y), fminf(v.z, v.w)));
        mx = fmaxf(mx, fmaxf(fmaxf(v.x, v.y), fmaxf(v.z, v.w)));
    }
#pragma unroll
    for (int off = 32; off > 0; off >>= 1) {
        mn = fminf(mn, __shfl_down(mn, off, 64));
        mx = fmaxf(mx, __shfl_down(mx, off, 64));
    }
    __shared__ float smn[4], smx[4];
    if ((tid & 63) == 0) { smn[tid >> 6] = mn; smx[tid >> 6] = mx; }
    __syncthreads();
    if (tid == 0) {
        mn = fminf(fminf(smn[0], smn[1]), fminf(smn[2], smn[3]));
        mx = fmaxf(fmaxf(smx[0], smx[1]), fmaxf(smx[2], smx[3]));
        ws[blockIdx.x] = mn;
        ws[256 + blockIdx.x] = mx;
    }
}

// ---------------- Kernel 2: fused final-reduce + main ----------------
// Grid must be exactly nrows/256 blocks (nrows = 1048576 -> 4096 blocks).
__global__ __launch_bounds__(256) void k_bspline(
    const float* __restrict__ x, const float* __restrict__ knots,
    const float* __restrict__ ws, float* __restrict__ out) {
    __shared__ float t[64];
    __shared__ float4 sN[256];   // 4 nonzero basis values per row
    __shared__ int sBase[256];   // first nonzero column per row
    __shared__ float smn[4], smx[4];
    __shared__ float sParam[2];  // xmin, range

    const int tid = threadIdx.x;
    if (tid < 64) t[tid] = knots[tid];

    // ---- Redundant final min/max reduce (2 KB of L2-hot partials) ----
    {
        float mn = ws[tid];
        float mx = ws[256 + tid];
#pragma unroll
        for (int off = 32; off > 0; off >>= 1) {
            mn = fminf(mn, __shfl_down(mn, off, 64));
            mx = fmaxf(mx, __shfl_down(mx, off, 64));
        }
        if ((tid & 63) == 0) { smn[tid >> 6] = mn; smx[tid >> 6] = mx; }
        __syncthreads();
        if (tid == 0) {
            mn = fminf(fminf(smn[0], smn[1]), fminf(smn[2], smn[3]));
            mx = fmaxf(fmaxf(smx[0], smx[1]), fmaxf(smx[2], smx[3]));
            sParam[0] = mn;
            // fp32 add, same as the fp32 reference: the 1e-8 is rounded away
            // for range ~9.7 -> max element normalizes to exactly 1.0.
            sParam[1] = (mx - mn) + 1e-8f;
        }
        __syncthreads();
    }
    const float xmin = sParam[0];
    const float range = sParam[1];

    // ---- Phase 1: one thread = one row; local de Boor (P-T A2.2) ----
    const int row = blockIdx.x * 256 + tid;
    const float xn = (x[row] - xmin) / range;  // fp32, bitwise-matches ref

    // Half-open indicator: xn >= 1.0 (the max element) -> all-zero row.
    const bool live = (xn < 1.0f) && (xn >= 0.0f);

    // Interval i with t[i] <= xn < t[i+1]; interior intervals are uniform
    // width ~1/57 starting at t[3]=0: floor guess, adjust vs actual knots.
    int ii = (int)(xn * 57.0f);
    ii = ii < 0 ? 0 : (ii > 56 ? 56 : ii);
    int i = ii + 3;
    if (xn < t[i]) i -= 1;
    else if (xn >= t[i + 1]) i += 1;
    i = i < 3 ? 3 : (i > 59 ? 59 : i);

    const float l1 = xn - t[i];
    const float l2 = xn - t[i - 1];
    const float l3 = xn - t[i - 2];
    const float r1 = t[i + 1] - xn;
    const float r2 = t[i + 2] - xn;
    const float r3 = t[i + 3] - xn;

    float N0 = 1.0f, N1, N2, N3, temp, saved;
    // d = 1
    temp = N0 * fast_rcp(r1 + l1);
    N0 = r1 * temp;
    N1 = l1 * temp;
    // d = 2
    temp = N0 * fast_rcp(r1 + l2);
    N0 = r1 * temp;
    saved = l2 * temp;
    temp = N1 * fast_rcp(r2 + l1);
    N1 = saved + r2 * temp;
    N2 = l1 * temp;
    // d = 3
    temp = N0 * fast_rcp(r1 + l3);
    N0 = r1 * temp;
    saved = l3 * temp;
    temp = N1 * fast_rcp(r2 + l2);
    N1 = saved + r2 * temp;
    saved = l2 * temp;
    temp = N2 * fast_rcp(r3 + l1);
    N2 = saved + r3 * temp;
    N3 = l1 * temp;

    const float g = live ? 1.0f : 0.0f;  // zero the boundary row
    float4 Nv;
    Nv.x = N0 * g; Nv.y = N1 * g; Nv.z = N2 * g; Nv.w = N3 * g;
    sN[tid] = Nv;
    sBase[tid] = i - 3;  // 0..56
    __syncthreads();

    // ---- Phase 2: cooperative, fully-coalesced NT write-out ----
    // Block's span: 256 rows * 15 float4 = 3840 contiguous float4s.
    // Thread tid writes p = tid + it*256 -> consecutive lanes, consecutive
    // float4s: 1 KB per wave-store, 16 cache lines (vs 64 strided).
    // Incremental (r,j): p+256 -> r+=17, j+=1, carry when j wraps past 14
    // (256 = 17*15 + 1).
    float4* __restrict__ o4 = (float4*)out + (size_t)blockIdx.x * 3840;
    int r = (unsigned)tid / 15u;
    int j = tid - r * 15;
#pragma unroll
    for (int it = 0; it < 15; ++it) {
        const float4 N = sN[r];  // <=5 distinct rows per wave (2-way free)
        const int b = sBase[r];
        const int d0 = (j << 2) - b;
        float4 v;
        v.x = (d0 == 0) ? N.x : (d0 == 1) ? N.y : (d0 == 2) ? N.z : (d0 == 3) ? N.w : 0.0f;
        const int d1 = d0 + 1;
        v.y = (d1 == 0) ? N.x : (d1 == 1) ? N.y : (d1 == 2) ? N.z : (d1 == 3) ? N.w : 0.0f;
        const int d2 = d0 + 2;
        v.z = (d2 == 0) ? N.x : (d2 == 1) ? N.y : (d2 == 2) ? N.z : (d2 == 3) ? N.w : 0.0f;
        const int d3 = d0 + 3;
        v.w = (d3 == 0) ? N.x : (d3 == 1) ? N.y : (d3 == 2) ? N.z : (d3 == 3) ? N.w : 0.0f;
        __builtin_nontemporal_store(*(const f32x4_t*)&v,
                                    (f32x4_t*)&o4[tid + it * 256]);
        r += 17; j += 1;
        if (j >= 15) { j -= 15; r += 1; }
    }
}

extern "C" void kernel_launch(void* const* d_in, const int* in_sizes, int n_in,
                              void* d_out, int out_size, void* d_ws, size_t ws_size,
                              hipStream_t stream) {
    const float* x = (const float*)d_in[0];
    const float* knots = (const float*)d_in[1];
    float* out = (float*)d_out;
    float* ws = (float*)d_ws;
    const int nrows = in_sizes[0];

    k_partial_minmax<<<256, 256, 0, stream>>>(x, ws, nrows / 4);
    k_bspline<<<nrows / 256, 256, 0, stream>>>(x, knots, ws, out);
}

// Round 7
// 249.994 us; speedup vs baseline: 1.0500x; 1.0500x over previous
//
#include <hip/hip_runtime.h>

// BSplineBasis: x[1048576], knots[64] (clamped cubic, 57 uniform interior
// intervals) -> out[1048576, 60] float32.
//
// FINAL (R6 post-mortem): this is the R5 best-measured variant (251.1 us),
// with R6's nontemporal-store experiment reverted (neutral after normalizing
// for run-to-run clock variance — fills slowed 5% that run too).
//
// Structure (R2-R5 ladder):
//  - Only 4 of 60 basis values are nonzero per row (cubic local support):
//    local de Boor triangle (Piegl-Tiller A2.2), ~30 VALU ops/row.
//  - Phase 2 writes the block's 3840 contiguous float4s lane-consecutive
//    (fully coalesced, 16 lines/wave-store). The naive per-row strided
//    write was 64 lines/wave-store and cost ~70 us extra (R2->R3).
//  - 4096 independent blocks: the cooperative single-kernel fusion (R4)
//    lost 2x on the main phase from TLP starvation. Final min/max reduce
//    is fused into the main kernel's head instead (redundant per-block
//    reduce of 256 L2-hot partials).
//  - Main kernel ~46-50 us vs ~40 us mandatory-traffic floor (240 MiB out
//    + 8 MiB in at ~6.4 TB/s achievable); the other ~190 us of dur_us is
//    the harness's per-replay 960 MiB d_ws + 240 MiB d_out poison fills.
//
// Reference quirk we must reproduce: xn = (x - min)/(max - min + 1e-8) in
// fp32 loses the 1e-8 (range ~9.7, ulp ~1e-6), so the max element has
// xn == 1.0 exactly. The reference's half-open degree-0 indicator
// (x >= t[j]) & (x < t[j+1]) then yields an ALL-ZERO row for that element.
//
// Workspace (floats): [0..255] block mins, [256..511] block maxs (2 KB).

#define N_BASIS 60

__device__ __forceinline__ float fast_rcp(float a) {
    return __builtin_amdgcn_rcpf(a);  // ~1 ulp; threshold is 2e-2, fine
}

// ---------------- Kernel 1: per-block partial min/max ----------------
__global__ __launch_bounds__(256) void k_partial_minmax(
    const float* __restrict__ x, float* __restrict__ ws, int n4) {
    const int tid = threadIdx.x;
    int gid = blockIdx.x * 256 + tid;
    const int stride = gridDim.x * 256;
    const float4* __restrict__ x4 = (const float4*)x;

    float mn = 3.4028235e38f, mx = -3.4028235e38f;
    for (int i = gid; i < n4; i += stride) {
        float4 v = x4[i];
        mn = fminf(mn, fminf(fminf(v.x, v.y), fminf(v.z, v.w)));
        mx = fmaxf(mx, fmaxf(fmaxf(v.x, v.y), fmaxf(v.z, v.w)));
    }
#pragma unroll
    for (int off = 32; off > 0; off >>= 1) {
        mn = fminf(mn, __shfl_down(mn, off, 64));
        mx = fmaxf(mx, __shfl_down(mx, off, 64));
    }
    __shared__ float smn[4], smx[4];
    if ((tid & 63) == 0) { smn[tid >> 6] = mn; smx[tid >> 6] = mx; }
    __syncthreads();
    if (tid == 0) {
        mn = fminf(fminf(smn[0], smn[1]), fminf(smn[2], smn[3]));
        mx = fmaxf(fmaxf(smx[0], smx[1]), fmaxf(smx[2], smx[3]));
        ws[blockIdx.x] = mn;
        ws[256 + blockIdx.x] = mx;
    }
}

// ---------------- Kernel 2: fused final-reduce + main ----------------
// Grid must be exactly nrows/256 blocks (nrows = 1048576 -> 4096 blocks).
__global__ __launch_bounds__(256) void k_bspline(
    const float* __restrict__ x, const float* __restrict__ knots,
    const float* __restrict__ ws, float* __restrict__ out) {
    __shared__ float t[64];
    __shared__ float4 sN[256];   // 4 nonzero basis values per row
    __shared__ int sBase[256];   // first nonzero column per row
    __shared__ float smn[4], smx[4];
    __shared__ float sParam[2];  // xmin, range

    const int tid = threadIdx.x;
    if (tid < 64) t[tid] = knots[tid];

    // ---- Redundant final min/max reduce (2 KB of L2-hot partials) ----
    {
        float mn = ws[tid];
        float mx = ws[256 + tid];
#pragma unroll
        for (int off = 32; off > 0; off >>= 1) {
            mn = fminf(mn, __shfl_down(mn, off, 64));
            mx = fmaxf(mx, __shfl_down(mx, off, 64));
        }
        if ((tid & 63) == 0) { smn[tid >> 6] = mn; smx[tid >> 6] = mx; }
        __syncthreads();
        if (tid == 0) {
            mn = fminf(fminf(smn[0], smn[1]), fminf(smn[2], smn[3]));
            mx = fmaxf(fmaxf(smx[0], smx[1]), fmaxf(smx[2], smx[3]));
            sParam[0] = mn;
            // fp32 add, same as the fp32 reference: the 1e-8 is rounded away
            // for range ~9.7 -> max element normalizes to exactly 1.0.
            sParam[1] = (mx - mn) + 1e-8f;
        }
        __syncthreads();
    }
    const float xmin = sParam[0];
    const float range = sParam[1];

    // ---- Phase 1: one thread = one row; local de Boor (P-T A2.2) ----
    const int row = blockIdx.x * 256 + tid;
    const float xn = (x[row] - xmin) / range;  // fp32, bitwise-matches ref

    // Half-open indicator: xn >= 1.0 (the max element) -> all-zero row.
    const bool live = (xn < 1.0f) && (xn >= 0.0f);

    // Interval i with t[i] <= xn < t[i+1]; interior intervals are uniform
    // width ~1/57 starting at t[3]=0: floor guess, adjust vs actual knots.
    int ii = (int)(xn * 57.0f);
    ii = ii < 0 ? 0 : (ii > 56 ? 56 : ii);
    int i = ii + 3;
    if (xn < t[i]) i -= 1;
    else if (xn >= t[i + 1]) i += 1;
    i = i < 3 ? 3 : (i > 59 ? 59 : i);

    const float l1 = xn - t[i];
    const float l2 = xn - t[i - 1];
    const float l3 = xn - t[i - 2];
    const float r1 = t[i + 1] - xn;
    const float r2 = t[i + 2] - xn;
    const float r3 = t[i + 3] - xn;

    float N0 = 1.0f, N1, N2, N3, temp, saved;
    // d = 1
    temp = N0 * fast_rcp(r1 + l1);
    N0 = r1 * temp;
    N1 = l1 * temp;
    // d = 2
    temp = N0 * fast_rcp(r1 + l2);
    N0 = r1 * temp;
    saved = l2 * temp;
    temp = N1 * fast_rcp(r2 + l1);
    N1 = saved + r2 * temp;
    N2 = l1 * temp;
    // d = 3
    temp = N0 * fast_rcp(r1 + l3);
    N0 = r1 * temp;
    saved = l3 * temp;
    temp = N1 * fast_rcp(r2 + l2);
    N1 = saved + r2 * temp;
    saved = l2 * temp;
    temp = N2 * fast_rcp(r3 + l1);
    N2 = saved + r3 * temp;
    N3 = l1 * temp;

    const float g = live ? 1.0f : 0.0f;  // zero the boundary row
    float4 Nv;
    Nv.x = N0 * g; Nv.y = N1 * g; Nv.z = N2 * g; Nv.w = N3 * g;
    sN[tid] = Nv;
    sBase[tid] = i - 3;  // 0..56
    __syncthreads();

    // ---- Phase 2: cooperative, fully-coalesced write-out ----
    // Block's span: 256 rows * 15 float4 = 3840 contiguous float4s.
    // Thread tid writes p = tid + it*256 -> consecutive lanes, consecutive
    // float4s: 1 KB per wave-store, 16 cache lines (vs 64 strided).
    // Incremental (r,j): p+256 -> r+=17, j+=1, carry when j wraps past 14
    // (256 = 17*15 + 1).
    float4* __restrict__ o4 = (float4*)out + (size_t)blockIdx.x * 3840;
    int r = (unsigned)tid / 15u;
    int j = tid - r * 15;
#pragma unroll
    for (int it = 0; it < 15; ++it) {
        const float4 N = sN[r];  // <=5 distinct rows per wave (2-way free)
        const int b = sBase[r];
        const int d0 = (j << 2) - b;
        float4 v;
        v.x = (d0 == 0) ? N.x : (d0 == 1) ? N.y : (d0 == 2) ? N.z : (d0 == 3) ? N.w : 0.0f;
        const int d1 = d0 + 1;
        v.y = (d1 == 0) ? N.x : (d1 == 1) ? N.y : (d1 == 2) ? N.z : (d1 == 3) ? N.w : 0.0f;
        const int d2 = d0 + 2;
        v.z = (d2 == 0) ? N.x : (d2 == 1) ? N.y : (d2 == 2) ? N.z : (d2 == 3) ? N.w : 0.0f;
        const int d3 = d0 + 3;
        v.w = (d3 == 0) ? N.x : (d3 == 1) ? N.y : (d3 == 2) ? N.z : (d3 == 3) ? N.w : 0.0f;
        o4[tid + it * 256] = v;
        r += 17; j += 1;
        if (j >= 15) { j -= 15; r += 1; }
    }
}

extern "C" void kernel_launch(void* const* d_in, const int* in_sizes, int n_in,
                              void* d_out, int out_size, void* d_ws, size_t ws_size,
                              hipStream_t stream) {
    const float* x = (const float*)d_in[0];
    const float* knots = (const float*)d_in[1];
    float* out = (float*)d_out;
    float* ws = (float*)d_ws;
    const int nrows = in_sizes[0];

    k_partial_minmax<<<256, 256, 0, stream>>>(x, ws, nrows / 4);
    k_bspline<<<nrows / 256, 256, 0, stream>>>(x, knots, ws, out);
}